// Round 11
// baseline (199.445 us; speedup 1.0000x reference)
//
#include <hip/hip_runtime.h>

#define B    64
#define K    512
#define C    4
#define NL   5
#define BK   (B*K)
#define ROWS 128            // rows of Habs2 per block (quartet split)
#define NT   1024           // threads per block (16 waves)
#define GRID (B*4)          // 256 blocks = 1 per CU

typedef float f2 __attribute__((ext_vector_type(2)));

// ---- LDS layout (bytes). part oversized so block footprint >80 KiB ->
// exactly 1 block/CU (deterministic, even spread across 256 CUs).
#define PART_OFF   0                     // float[16(+20 pad)][512]
#define VST_OFF    (36*K*4)              // float2[512]
#define XSQ_OFF    (VST_OFF + K*8)       // float[512]
#define MPL_OFF    (XSQ_OFF + K*4)       // float[512]
#define NZ_OFF     (MPL_OFF + K*4)       // float[128]
#define DAB_OFF    (NZ_OFF + ROWS*4)     // float[128]
#define SMEM_BYTES (DAB_OFF + ROWS*4)    // 82944 B

// ---- L3-direct (bypass L1/L2) data ops: relaxed agent-scope atomics --------
__device__ __forceinline__ float ld_l3(const float* p) {
    return __uint_as_float(__hip_atomic_load((const unsigned*)p,
        __ATOMIC_RELAXED, __HIP_MEMORY_SCOPE_AGENT));
}
__device__ __forceinline__ void st_l3(float* p, float v) {
    __hip_atomic_store((unsigned*)p, __float_as_uint(v),
        __ATOMIC_RELAXED, __HIP_MEMORY_SCOPE_AGENT);
}
__device__ __forceinline__ void st_l3_2(float2* p, float2 v) {
    unsigned long long u = ((unsigned long long)__float_as_uint(v.y) << 32)
                         | (unsigned long long)__float_as_uint(v.x);
    __hip_atomic_store((unsigned long long*)p, u,
        __ATOMIC_RELAXED, __HIP_MEMORY_SCOPE_AGENT);
}
__device__ __forceinline__ float2 ld_l3_2(const float2* p) {
    unsigned long long u = __hip_atomic_load((const unsigned long long*)p,
        __ATOMIC_RELAXED, __HIP_MEMORY_SCOPE_AGENT);
    return make_float2(__uint_as_float((unsigned)(u & 0xffffffffu)),
                       __uint_as_float((unsigned)(u >> 32)));
}

// ---- DPP wave64 sum reduction (VALU pipe, zero LDS traffic) ---------------
template <int CTRL, int ROWMASK>
__device__ __forceinline__ float dppadd(float x) {
    int t = __builtin_amdgcn_update_dpp(0, __float_as_int(x), CTRL, ROWMASK,
                                        0xf, true);
    return x + __int_as_float(t);
}
__device__ __forceinline__ float wsum(float x) {
    x = dppadd<0x111, 0xf>(x);   // row_shr:1
    x = dppadd<0x112, 0xf>(x);   // row_shr:2
    x = dppadd<0x114, 0xf>(x);   // row_shr:4
    x = dppadd<0x118, 0xf>(x);   // row_shr:8
    x = dppadd<0x142, 0xa>(x);   // row_bcast:15 -> rows 1,3
    x = dppadd<0x143, 0xc>(x);   // row_bcast:31 -> rows 2,3
    return __int_as_float(__builtin_amdgcn_readlane(__float_as_int(x), 63));
}

// ---------------------------------------------------------------------------
// Quartet-split persistent kernel, f32 register-resident fragments.
// Block (b = blockIdx&63, q = blockIdx>>6) owns rows j0..j0+127 of batch b.
// Fragment mapping: thread (w, lane) holds rows {16i+w}, cols
// {t*128 + lane*2 + e} as float h[8][8] in VGPRs (64 regs; no per-layer
// fp16->f32 converts -> P1/P2 are pure v_fma_f32; also removes the last
// fp16 rounding source). Global loads dwordx2 (BW-bound); all induced LDS
// accesses are 2-way bank aliases (free). Per layer: P1 dot (regs+DPP->
// SGPR); per-row algebra on lanes 0-7; P2 transposed matvec (regs) -> LDS
// reduce -> L3 partial; fence-free monotonic quartet barrier; FIN whole
// batch (redundant x4, vst/xsq block-local). Cross-block data L3-direct.
// ---------------------------------------------------------------------------
__global__ __launch_bounds__(NT, 4) void k_all(
    const float* __restrict__ hre,  const float* __restrict__ him,
    const float* __restrict__ noise,const float* __restrict__ mp,
    const float* __restrict__ vre,  const float* __restrict__ vim,
    const float* __restrict__ ar_re,const float* __restrict__ ar_im,
    const float* __restrict__ dl_re,const float* __restrict__ dl_im,
    const float* __restrict__ rc_re,const float* __restrict__ rc_im,
    float2* __restrict__ vtilde,    // [2][BK]
    float*  __restrict__ ulpart,    // [2][B*4][K]
    unsigned* __restrict__ bar,     // 64 quartets x 32 uints (128 B)
    float* __restrict__ out)        // [NL][BK][2]
{
    extern __shared__ char smem[];
    float*  part = (float*) (smem + PART_OFF);
    float2* vst  = (float2*)(smem + VST_OFF);
    float*  xsq  = (float*) (smem + XSQ_OFF);
    float*  mpl  = (float*) (smem + MPL_OFF);
    float*  nz   = (float*) (smem + NZ_OFF);
    float*  dab  = (float*) (smem + DAB_OFF);

    const int tid  = threadIdx.x;
    const int lane = tid & 63;
    const int w    = tid >> 6;
    const int b    = blockIdx.x & 63;          // XCD-local quartet mapping
    const int q    = blockIdx.x >> 6;
    const int j0   = q * ROWS;
    unsigned* qb   = bar + ((unsigned)b << 5);

    // ---------------- init: v state, |v|^2, maxpow, noise -------------------
    if (tid < K) {
        float a = vre[b * K + tid], c2 = vim[b * K + tid];
        vst[tid] = make_float2(a, c2);
        xsq[tid] = a * a + c2 * c2;
        mpl[tid] = mp[b * K + tid];
    } else if (tid < K + ROWS) {
        nz[tid - K] = noise[b * K + j0 + (tid - K)];
    }
    __syncthreads();

    const f2* xp = (const f2*)xsq;                 // f2 index: col/2
    float xq[8];                                   // xq[2t+e] = xsq[t*128+2*lane+e]
#pragma unroll
    for (int t = 0; t < 4; ++t) {
        f2 x = xp[t * 64 + lane];
        xq[2 * t] = x.x; xq[2 * t + 1] = x.y;
    }

    // ---------------- HBM stream -> f32 register fragments + fused l0 P1 ---
    float h[8][8];                                 // h[i][2t+e]
    float rs0[8];                                  // uniform row sums (l=0)
    {
        const size_t gb = ((size_t)b * K + j0) * K;     // float offset
        const f2* rp = (const f2*)(hre + gb);           // f2 offset = /2
        const f2* ip = (const f2*)(him + gb);
        f2 ra[2][4], ia[2][4];
#pragma unroll
        for (int t = 0; t < 4; ++t) {
            ra[0][t] = __builtin_nontemporal_load(rp + (size_t)w * 256 + t * 64 + lane);
            ia[0][t] = __builtin_nontemporal_load(ip + (size_t)w * 256 + t * 64 + lane);
        }
#pragma unroll
        for (int i = 0; i < 8; ++i) {
            const int cur = i & 1, nxt = cur ^ 1;
            if (i < 7) {
                const size_t rb = (size_t)(16 * (i + 1) + w) * 256;  // f2 units
#pragma unroll
                for (int t = 0; t < 4; ++t) {
                    ra[nxt][t] = __builtin_nontemporal_load(rp + rb + t * 64 + lane);
                    ia[nxt][t] = __builtin_nontemporal_load(ip + rb + t * 64 + lane);
                }
            }
            float acc = 0.f;
#pragma unroll
            for (int t = 0; t < 4; ++t) {
                const f2 r = ra[cur][t], m = ia[cur][t];
                h[i][2*t]   = r.x * r.x + m.x * m.x;
                h[i][2*t+1] = r.y * r.y + m.y * m.y;
                acc += h[i][2*t] * xq[2*t] + h[i][2*t+1] * xq[2*t+1];
            }
            const int row = 16 * i + w;
            const int j   = j0 + row;              // diag at global col j
            if (lane == ((j & 127) >> 1)) dab[row] = h[i][((j >> 7) << 1) | (j & 1)];
            rs0[i] = wsum(acc);                    // fused layer-0 P1
        }
    }

    for (int l = 0; l < NL; ++l) {
        const int buf = l & 1;
        // ---------------- P1: row sums (regs + DPP -> SGPR) ----------------
        float scov[8];
        if (l == 0) {
#pragma unroll
            for (int r = 0; r < 8; ++r) scov[r] = rs0[r];
        } else {
#pragma unroll
            for (int t = 0; t < 4; ++t) {          // 2-way LDS alias: free
                f2 x = xp[t * 64 + lane];
                xq[2 * t] = x.x; xq[2 * t + 1] = x.y;
            }
#pragma unroll
            for (int r = 0; r < 8; ++r) {
                float acc = 0.f;
#pragma unroll
                for (int t = 0; t < 8; ++t) acc += h[r][t] * xq[t];
                scov[r] = wsum(acc);
            }
        }
        // ---------------- per-row algebra: lane r owns row 16*r + w --------
        float ulv_own = 0.f;
        if (lane < 8) {
            float s = scov[0];
#pragma unroll
            for (int r = 1; r < 8; ++r) s = (lane == r) ? scov[r] : s;
            const int row = 16 * lane + w;
            const int j   = j0 + row;
            const int bj  = b * K + j;
            const float cov = s + nz[row];
            const float d2  = dab[row];
            const float A   = d2 * xsq[j];
            const float ww  = cov / (cov - A);     // w is real, > 0
            const float sc  = d2 * ww / cov;
            const float2 vv = vst[j];
            st_l3_2(&vtilde[buf * BK + bj], make_float2(sc * vv.x, sc * vv.y));
            ulv_own = A * ww / (cov * cov);        // |u|^2 |w|
        }
        float ulv[8];                              // uniform (SGPR)
#pragma unroll
        for (int r = 0; r < 8; ++r)
            ulv[r] = __int_as_float(
                __builtin_amdgcn_readlane(__float_as_int(ulv_own), r));

        // ---------------- P2: transposed matvec from register fragments ----
        f2* pp = (f2*)part;
#pragma unroll
        for (int t = 0; t < 4; ++t) {
            float a0 = 0.f, a1 = 0.f;
#pragma unroll
            for (int r = 0; r < 8; ++r) {
                a0 += h[r][2*t]   * ulv[r];
                a1 += h[r][2*t+1] * ulv[r];
            }
            f2 v; v.x = a0; v.y = a1;
            pp[w * 256 + t * 64 + lane] = v;       // 2-way alias: free
        }
        __syncthreads();                           // sync 1

        float s2 = 0.f;                            // own quartet partial
        if (tid < K) {
#pragma unroll
            for (int ws2 = 0; ws2 < 16; ++ws2) s2 += part[ws2 * K + tid];
            st_l3(&ulpart[(size_t)buf * (B*4*K) + ((size_t)(b*4 + q)) * K + tid],
                  s2);
        }
        __syncthreads();                           // sync 2: drain st_l3
        if (tid == 0)
            __hip_atomic_fetch_add(qb, 1u, __ATOMIC_RELAXED,
                                   __HIP_MEMORY_SCOPE_AGENT);
        if (lane == 0) {                           // per-wave poll exit
            const unsigned target = 4u * (unsigned)(l + 1);
            while (__hip_atomic_load(qb, __ATOMIC_RELAXED,
                                     __HIP_MEMORY_SCOPE_AGENT) < target)
                __builtin_amdgcn_s_sleep(1);
        }
        asm volatile("" ::: "memory");             // no hoisting past poll

        // ---------------- FIN: whole batch row (redundant x4) --------------
        if (tid < K) {
            const int k  = tid;
            const int bk = b * K + k;
            const float* up = ulpart + (size_t)buf * (B*4*K) + (size_t)(b*4) * K;
            const float2 vt = ld_l3_2(&vtilde[buf * BK + bk]);
            float ul = s2;                         // own partial: register
#pragma unroll
            for (int qq = 0; qq < 4; ++qq)
                if (qq != q) ul += ld_l3(up + qq * K + k);
            const float p   = mpl[k];
            const float avt = sqrtf(vt.x*vt.x + vt.y*vt.y);
            const float mu  = fmaxf(avt / sqrtf(p) - ul, 0.f);
            const float inv = 1.f / (ul + mu);
            float ax = 0.f, ay = 0.f;
#pragma unroll
            for (int c = 0; c < C; ++c) {
                const float gre = ar_re[c] * inv + dl_re[c];
                const float gim = ar_im[c] * inv + dl_im[c];
                float zre = vt.x * gre - vt.y * gim;
                float zim = vt.x * gim + vt.y * gre;
                zre = fmaxf(zre, 0.f);             // CReLU
                zim = fmaxf(zim, 0.f);
                ax += zre * rc_re[c] - zim * rc_im[c];
                ay += zre * rc_im[c] + zim * rc_re[c];
            }
            const float n2   = ax*ax + ay*ay;
            const float cur  = fmaxf(p, n2);
            const float corr = fminf(sqrtf(p / cur), 1.f);
            ax *= corr; ay *= corr;
            if ((k >> 7) == q)                     // owner writes out
                ((float2*)out)[(size_t)l * BK + bk] = make_float2(ax, ay);
            vst[k] = make_float2(ax, ay);
            xsq[k] = ax * ax + ay * ay;
        }
        __syncthreads();                           // sync 3
    }
}

// ---------------------------------------------------------------------------
extern "C" void kernel_launch(void* const* d_in, const int* in_sizes, int n_in,
                              void* d_out, int out_size, void* d_ws, size_t ws_size,
                              hipStream_t stream) {
    const float* hre   = (const float*)d_in[0];
    const float* him   = (const float*)d_in[1];
    const float* noise = (const float*)d_in[2];
    const float* mp    = (const float*)d_in[3];
    const float* vre   = (const float*)d_in[4];
    const float* vim   = (const float*)d_in[5];
    const float* ar_re = (const float*)d_in[6];
    const float* ar_im = (const float*)d_in[7];
    const float* dl_re = (const float*)d_in[8];
    const float* dl_im = (const float*)d_in[9];
    const float* rc_re = (const float*)d_in[10];
    const float* rc_im = (const float*)d_in[11];
    float* out = (float*)d_out;

    char*     ws     = (char*)d_ws;
    float2*   vtilde = (float2*)ws;                               // 512 KB
    float*    ulpart = (float*)(ws + 2*(size_t)BK*8);             // 1 MB
    unsigned* bar    = (unsigned*)(ws + 2*(size_t)BK*8 + 2*(size_t)B*4*K*4);

    static bool attr_done = false;
    if (!attr_done) {
        (void)hipFuncSetAttribute((const void*)k_all,
                                  hipFuncAttributeMaxDynamicSharedMemorySize,
                                  SMEM_BYTES);
        attr_done = true;
    }

    // monotonic barrier counters must be zero at kernel start on every replay
    (void)hipMemsetAsync(bar, 0, B * 32 * sizeof(unsigned), stream);

    hipLaunchKernelGGL(k_all, dim3(GRID), dim3(NT), SMEM_BYTES, stream,
                       hre, him, noise, mp, vre, vim,
                       ar_re, ar_im, dl_re, dl_im, rc_re, rc_im,
                       vtilde, ulpart, bar, out);
}

// Round 12
// 177.504 us; speedup vs baseline: 1.1236x; 1.1236x over previous
//
#include <hip/hip_runtime.h>

#define B    64
#define K    512
#define C    4
#define NL   5
#define BK   (B*K)
#define ROWS 128            // rows of Habs2 per block (quartet split)
#define NT   1024           // threads per block (16 waves)
#define GRID (B*4)          // 256 blocks = 1 per CU

typedef _Float16 half_t;
typedef _Float16 half8 __attribute__((ext_vector_type(8)));
typedef float    f2    __attribute__((ext_vector_type(2)));
typedef unsigned u32x4 __attribute__((ext_vector_type(4)));

// ---- LDS layout (bytes). part oversized so block footprint >80 KiB ->
// exactly 1 block/CU (deterministic, even spread across 256 CUs).
#define PART_OFF   0                     // float[16(+20 pad)][512]
#define VST_OFF    (36*K*4)              // float2[512]
#define XSQ_OFF    (VST_OFF + K*8)       // float[512]
#define MPL_OFF    (XSQ_OFF + K*4)       // float[512]
#define NZ_OFF     (MPL_OFF + K*4)       // float[128]
#define DAB_OFF    (NZ_OFF + ROWS*4)     // float[128]
#define SMEM_BYTES (DAB_OFF + ROWS*4)    // 82944 B

// ---- L3-direct (bypass L1/L2) data ops: relaxed agent-scope atomics --------
__device__ __forceinline__ float ld_l3(const float* p) {
    return __uint_as_float(__hip_atomic_load((const unsigned*)p,
        __ATOMIC_RELAXED, __HIP_MEMORY_SCOPE_AGENT));
}
__device__ __forceinline__ void st_l3(float* p, float v) {
    __hip_atomic_store((unsigned*)p, __float_as_uint(v),
        __ATOMIC_RELAXED, __HIP_MEMORY_SCOPE_AGENT);
}
__device__ __forceinline__ void st_l3u(unsigned* p, unsigned v) {
    __hip_atomic_store(p, v, __ATOMIC_RELAXED, __HIP_MEMORY_SCOPE_AGENT);
}
__device__ __forceinline__ void st_l3_2(float2* p, float2 v) {
    unsigned long long u = ((unsigned long long)__float_as_uint(v.y) << 32)
                         | (unsigned long long)__float_as_uint(v.x);
    __hip_atomic_store((unsigned long long*)p, u,
        __ATOMIC_RELAXED, __HIP_MEMORY_SCOPE_AGENT);
}
__device__ __forceinline__ float2 ld_l3_2(const float2* p) {
    unsigned long long u = __hip_atomic_load((const unsigned long long*)p,
        __ATOMIC_RELAXED, __HIP_MEMORY_SCOPE_AGENT);
    return make_float2(__uint_as_float((unsigned)(u & 0xffffffffu)),
                       __uint_as_float((unsigned)(u >> 32)));
}
// one coherent 16B load of the quartet's 4 flag slots (per-dword atomicity)
__device__ __forceinline__ u32x4 ld_flags(const unsigned* p) {
    u32x4 r;
    asm volatile("global_load_dwordx4 %0, %1, off sc0 sc1\n\t"
                 "s_waitcnt vmcnt(0)"
                 : "=v"(r) : "v"(p) : "memory");
    return r;
}

// ---- DPP wave64 sum reduction (VALU pipe, zero LDS traffic) ---------------
template <int CTRL, int ROWMASK>
__device__ __forceinline__ float dppadd(float x) {
    int t = __builtin_amdgcn_update_dpp(0, __float_as_int(x), CTRL, ROWMASK,
                                        0xf, true);
    return x + __int_as_float(t);
}
__device__ __forceinline__ float wsum(float x) {
    x = dppadd<0x111, 0xf>(x);   // row_shr:1
    x = dppadd<0x112, 0xf>(x);   // row_shr:2
    x = dppadd<0x114, 0xf>(x);   // row_shr:4
    x = dppadd<0x118, 0xf>(x);   // row_shr:8
    x = dppadd<0x142, 0xa>(x);   // row_bcast:15 -> rows 1,3
    x = dppadd<0x143, 0xc>(x);   // row_bcast:31 -> rows 2,3
    return __int_as_float(__builtin_amdgcn_readlane(__float_as_int(x), 63));
}

// ---------------------------------------------------------------------------
// Quartet-split persistent kernel (r10 base), flag-line exchange barrier.
// Block (b = blockIdx&63, q = blockIdx>>6) owns rows j0..j0+127 of batch b,
// register-resident fp16 fragments: thread (w, lane) holds rows {16i+w},
// cols {t*128 + lane*2 + e} -> dwordx2 global loads (BW-bound); induced LDS
// accesses are free 2-way aliases. Per layer: P1 dot (regs+DPP->SGPR);
// per-row algebra on lanes 0-7; P2 transposed matvec -> LDS reduce -> L3
// partial; then sync2 (drains all sc1 stores: __syncthreads waits vmcnt(0))
// -> tid0 stores flag[q]=l+1 -> lane0 of waves 0-7 polls ONE dwordx4 of the
// flag line (3 slots >= tag); waves 8-15 skip (sync3 orders them). No RMW,
// one detect load. Monotonic tags + parity double-buffer: a writer can be at
// most one layer ahead (it must see our flag >= l+2 to pass its barrier),
// so the other parity is never overwritten under a reader. FIN redundant x4.
// ---------------------------------------------------------------------------
__global__ __launch_bounds__(NT, 4) void k_all(
    const float* __restrict__ hre,  const float* __restrict__ him,
    const float* __restrict__ noise,const float* __restrict__ mp,
    const float* __restrict__ vre,  const float* __restrict__ vim,
    const float* __restrict__ ar_re,const float* __restrict__ ar_im,
    const float* __restrict__ dl_re,const float* __restrict__ dl_im,
    const float* __restrict__ rc_re,const float* __restrict__ rc_im,
    float2* __restrict__ vtilde,    // [2][BK]
    float*  __restrict__ ulpart,    // [2][B*4][K]
    unsigned* __restrict__ bar,     // 64 quartets x 32 uints (flag lines)
    float* __restrict__ out)        // [NL][BK][2]
{
    extern __shared__ char smem[];
    float*  part = (float*) (smem + PART_OFF);
    float2* vst  = (float2*)(smem + VST_OFF);
    float*  xsq  = (float*) (smem + XSQ_OFF);
    float*  mpl  = (float*) (smem + MPL_OFF);
    float*  nz   = (float*) (smem + NZ_OFF);
    float*  dab  = (float*) (smem + DAB_OFF);

    const int tid  = threadIdx.x;
    const int lane = tid & 63;
    const int w    = tid >> 6;
    const int b    = blockIdx.x & 63;          // XCD-local quartet mapping
    const int q    = blockIdx.x >> 6;
    const int j0   = q * ROWS;
    unsigned* fl   = bar + ((unsigned)b << 5); // 16B-aligned flag line

    // ---------------- init: v state, |v|^2, maxpow, noise -------------------
    if (tid < K) {
        float a = vre[b * K + tid], c2 = vim[b * K + tid];
        vst[tid] = make_float2(a, c2);
        xsq[tid] = a * a + c2 * c2;
        mpl[tid] = mp[b * K + tid];
    } else if (tid < K + ROWS) {
        nz[tid - K] = noise[b * K + j0 + (tid - K)];
    }
    __syncthreads();

    const f2* xp = (const f2*)xsq;                 // f2 index: col/2
    float xq[8];                                   // xq[2t+e] = xsq[t*128+2*lane+e]
#pragma unroll
    for (int t = 0; t < 4; ++t) {
        f2 x = xp[t * 64 + lane];
        xq[2 * t] = x.x; xq[2 * t + 1] = x.y;
    }

    // ---------------- HBM stream -> fp16 register fragments + fused l0 P1 --
    half8 h[8];                                    // h[i][2t+e]
    float rs0[8];                                  // uniform row sums (l=0)
    {
        const size_t gb = ((size_t)b * K + j0) * K;     // float offset
        const f2* rp = (const f2*)(hre + gb);           // f2 offset = /2
        const f2* ip = (const f2*)(him + gb);
        f2 ra[2][4], ia[2][4];
#pragma unroll
        for (int t = 0; t < 4; ++t) {
            ra[0][t] = __builtin_nontemporal_load(rp + (size_t)w * 256 + t * 64 + lane);
            ia[0][t] = __builtin_nontemporal_load(ip + (size_t)w * 256 + t * 64 + lane);
        }
#pragma unroll
        for (int i = 0; i < 8; ++i) {
            const int cur = i & 1, nxt = cur ^ 1;
            if (i < 7) {
                const size_t rb = (size_t)(16 * (i + 1) + w) * 256;  // f2 units
#pragma unroll
                for (int t = 0; t < 4; ++t) {
                    ra[nxt][t] = __builtin_nontemporal_load(rp + rb + t * 64 + lane);
                    ia[nxt][t] = __builtin_nontemporal_load(ip + rb + t * 64 + lane);
                }
            }
            float s[8], acc = 0.f;
            half8 hh;
#pragma unroll
            for (int t = 0; t < 4; ++t) {
                const f2 r = ra[cur][t], m = ia[cur][t];
                s[2*t]   = r.x * r.x + m.x * m.x;
                s[2*t+1] = r.y * r.y + m.y * m.y;
                hh[2*t]   = (_Float16)s[2*t];
                hh[2*t+1] = (_Float16)s[2*t+1];
                acc += s[2*t] * xq[2*t] + s[2*t+1] * xq[2*t+1];
            }
            h[i] = hh;
            const int row = 16 * i + w;
            const int j   = j0 + row;              // diag at global col j
            if (lane == ((j & 127) >> 1)) dab[row] = s[((j >> 7) << 1) | (j & 1)];
            rs0[i] = wsum(acc);                    // fused layer-0 P1
        }
    }

    // FIN per-thread invariants (k = tid < 512), constant across layers
    float p_inv = 0.f, sp_inv = 1.f;
    if (tid < K) { p_inv = mpl[tid]; sp_inv = sqrtf(p_inv); }

    for (int l = 0; l < NL; ++l) {
        const int buf = l & 1;
        const unsigned tag = (unsigned)(l + 1);
        // ---------------- P1: row sums (regs + DPP -> SGPR) ----------------
        float scov[8];
        if (l == 0) {
#pragma unroll
            for (int r = 0; r < 8; ++r) scov[r] = rs0[r];
        } else {
#pragma unroll
            for (int t = 0; t < 4; ++t) {          // 2-way LDS alias: free
                f2 x = xp[t * 64 + lane];
                xq[2 * t] = x.x; xq[2 * t + 1] = x.y;
            }
#pragma unroll
            for (int r = 0; r < 8; ++r) {
                float acc = 0.f;
#pragma unroll
                for (int t = 0; t < 8; ++t) acc += (float)h[r][t] * xq[t];
                scov[r] = wsum(acc);
            }
        }
        // ---------------- per-row algebra: lane r owns row 16*r + w --------
        float ulv_own = 0.f;
        if (lane < 8) {
            float s = scov[0];
#pragma unroll
            for (int r = 1; r < 8; ++r) s = (lane == r) ? scov[r] : s;
            const int row = 16 * lane + w;
            const int j   = j0 + row;
            const int bj  = b * K + j;
            const float cov = s + nz[row];
            const float d2  = dab[row];
            const float A   = d2 * xsq[j];
            const float ww  = cov / (cov - A);     // w is real, > 0
            const float sc  = d2 * ww / cov;
            const float2 vv = vst[j];
            st_l3_2(&vtilde[buf * BK + bj], make_float2(sc * vv.x, sc * vv.y));
            ulv_own = A * ww / (cov * cov);        // |u|^2 |w|
        }
        float ulv[8];                              // uniform (SGPR)
#pragma unroll
        for (int r = 0; r < 8; ++r)
            ulv[r] = __int_as_float(
                __builtin_amdgcn_readlane(__float_as_int(ulv_own), r));

        // ---------------- P2: transposed matvec from register fragments ----
        f2* pp = (f2*)part;
#pragma unroll
        for (int t = 0; t < 4; ++t) {
            float a0 = 0.f, a1 = 0.f;
#pragma unroll
            for (int r = 0; r < 8; ++r) {
                a0 += (float)h[r][2*t]   * ulv[r];
                a1 += (float)h[r][2*t+1] * ulv[r];
            }
            f2 v; v.x = a0; v.y = a1;
            pp[w * 256 + t * 64 + lane] = v;       // 2-way alias: free
        }
        __syncthreads();                           // sync 1

        float s2 = 0.f;                            // own quartet partial
        if (tid < K) {
#pragma unroll
            for (int ws2 = 0; ws2 < 16; ++ws2) s2 += part[ws2 * K + tid];
            st_l3(&ulpart[(size_t)buf * (B*4*K) + ((size_t)(b*4 + q)) * K + tid],
                  s2);
        }
        __syncthreads();      // sync 2: every wave drained vmcnt(0) -> all
                              // partial/vtilde stores are at L3
        if (tid == 0) st_l3u(fl + q, tag);         // publish: plain store
        if (w < 8 && lane == 0) {                  // consumers only poll
            const int q1 = (q + 1) & 3, q2 = (q + 2) & 3, q3 = (q + 3) & 3;
            for (;;) {
                u32x4 f = ld_flags(fl);            // one 16B coherent load
                if (f[q1] >= tag && f[q2] >= tag && f[q3] >= tag) break;
                __builtin_amdgcn_s_sleep(1);
            }
        }
        asm volatile("" ::: "memory");             // no hoisting past poll

        // ---------------- FIN: whole batch row (redundant x4) --------------
        if (tid < K) {
            const int k  = tid;
            const int bk = b * K + k;
            const float* up = ulpart + (size_t)buf * (B*4*K) + (size_t)(b*4) * K;
            const float2 vt = ld_l3_2(&vtilde[buf * BK + bk]);
            float ul = s2;                         // own partial: register
#pragma unroll
            for (int qq = 0; qq < 4; ++qq)
                if (qq != q) ul += ld_l3(up + qq * K + k);
            const float avt = sqrtf(vt.x*vt.x + vt.y*vt.y);
            const float mu  = fmaxf(avt / sp_inv - ul, 0.f);
            const float inv = 1.f / (ul + mu);
            float ax = 0.f, ay = 0.f;
#pragma unroll
            for (int c = 0; c < C; ++c) {
                const float gre = ar_re[c] * inv + dl_re[c];
                const float gim = ar_im[c] * inv + dl_im[c];
                float zre = vt.x * gre - vt.y * gim;
                float zim = vt.x * gim + vt.y * gre;
                zre = fmaxf(zre, 0.f);             // CReLU
                zim = fmaxf(zim, 0.f);
                ax += zre * rc_re[c] - zim * rc_im[c];
                ay += zre * rc_im[c] + zim * rc_re[c];
            }
            const float n2   = ax*ax + ay*ay;
            const float cur  = fmaxf(p_inv, n2);
            const float corr = fminf(sqrtf(p_inv / cur), 1.f);
            ax *= corr; ay *= corr;
            if ((k >> 7) == q)                     // owner writes out
                ((float2*)out)[(size_t)l * BK + bk] = make_float2(ax, ay);
            vst[k] = make_float2(ax, ay);
            xsq[k] = ax * ax + ay * ay;
        }
        __syncthreads();                           // sync 3
    }
}

// ---------------------------------------------------------------------------
extern "C" void kernel_launch(void* const* d_in, const int* in_sizes, int n_in,
                              void* d_out, int out_size, void* d_ws, size_t ws_size,
                              hipStream_t stream) {
    const float* hre   = (const float*)d_in[0];
    const float* him   = (const float*)d_in[1];
    const float* noise = (const float*)d_in[2];
    const float* mp    = (const float*)d_in[3];
    const float* vre   = (const float*)d_in[4];
    const float* vim   = (const float*)d_in[5];
    const float* ar_re = (const float*)d_in[6];
    const float* ar_im = (const float*)d_in[7];
    const float* dl_re = (const float*)d_in[8];
    const float* dl_im = (const float*)d_in[9];
    const float* rc_re = (const float*)d_in[10];
    const float* rc_im = (const float*)d_in[11];
    float* out = (float*)d_out;

    char*     ws     = (char*)d_ws;
    float2*   vtilde = (float2*)ws;                               // 512 KB
    float*    ulpart = (float*)(ws + 2*(size_t)BK*8);             // 1 MB
    unsigned* bar    = (unsigned*)(ws + 2*(size_t)BK*8 + 2*(size_t)B*4*K*4);

    static bool attr_done = false;
    if (!attr_done) {
        (void)hipFuncSetAttribute((const void*)k_all,
                                  hipFuncAttributeMaxDynamicSharedMemorySize,
                                  SMEM_BYTES);
        attr_done = true;
    }

    // monotonic flags (1..5) must be zero at kernel start on every replay
    (void)hipMemsetAsync(bar, 0, B * 32 * sizeof(unsigned), stream);

    hipLaunchKernelGGL(k_all, dim3(GRID), dim3(NT), SMEM_BYTES, stream,
                       hre, him, noise, mp, vre, vim,
                       ar_re, ar_im, dl_re, dl_im, rc_re, rc_im,
                       vtilde, ulpart, bar, out);
}